// Round 3
// baseline (433.727 us; speedup 1.0000x reference)
//
#include <hip/hip_runtime.h>

#define D 32

// K0: P_src = W_aggr @ W_eu @ W_src, similarly edge, rx. One block (32,32).
__global__ void combine_weights(const float* __restrict__ W_src,
                                const float* __restrict__ W_edge,
                                const float* __restrict__ W_rx,
                                const float* __restrict__ W_eu,
                                const float* __restrict__ W_aggr,
                                float* __restrict__ P_out) {
    __shared__ float sWa[D][D], sWe[D][D], sP2[D][D + 1];
    __shared__ float sW1[D][D], sW2[D][D], sW3[D][D];
    const int j = threadIdx.x, i = threadIdx.y;
    sWa[i][j] = W_aggr[i * D + j];
    sWe[i][j] = W_eu[i * D + j];
    sW1[i][j] = W_src[i * D + j];
    sW2[i][j] = W_edge[i * D + j];
    sW3[i][j] = W_rx[i * D + j];
    __syncthreads();
    float s = 0.f;
    #pragma unroll
    for (int k = 0; k < D; ++k) s += sWa[i][k] * sWe[k][j];
    sP2[i][j] = s;
    __syncthreads();
    float a = 0.f, b = 0.f, c = 0.f;
    #pragma unroll
    for (int k = 0; k < D; ++k) {
        const float p = sP2[i][k];
        a += p * sW1[k][j];
        b += p * sW2[k][j];
        c += p * sW3[k][j];
    }
    P_out[0 * D * D + i * D + j] = a;
    P_out[1 * D * D + i * D + j] = b;
    P_out[2 * D * D + i * D + j] = c;
}

// K1: per-receiver degree histogram. 2M int atomics into 400KB (L2-resident).
__global__ void __launch_bounds__(256) count_edges(
    const int* __restrict__ ei, int* __restrict__ cnt, int E_) {
    const int e = blockIdx.x * 256 + threadIdx.x;
    if (e < E_) atomicAdd(&cnt[ei[E_ + e]], 1);
}

// K2: exact CSR allocation. Placement order is atomic-nondeterministic but
// contiguous per node; only affects fp32 summation order (within tolerance).
__global__ void __launch_bounds__(256) alloc_nodes(
    const int* __restrict__ cnt, int* __restrict__ cur, int* __restrict__ total, int N_) {
    const int n = blockIdx.x * 256 + threadIdx.x;
    if (n < N_) cur[n] = atomicAdd(total, cnt[n]);
}

// K3: CSR fill. int2{e,u} per edge, contiguous per receiver -> dirty-line
// coalescing (~8 entries/64B line vs 1 for the old strided bucket).
__global__ void __launch_bounds__(256) fill_csr(
    const int* __restrict__ ei, int* __restrict__ cur, int2* __restrict__ csr, int E_) {
    const int e = blockIdx.x * 256 + threadIdx.x;
    if (e >= E_) return;
    const int u = ei[e];
    const int v = ei[E_ + e];
    const int pos = atomicAdd(&cur[v], 1);
    csr[pos] = make_int2(e, u);
}

// K4: per-node gather-sum, atomic-free, exact allocation -> plain stores,
// no A/B pre-zeroing needed. 8 lanes per node, each owns a float4 slice.
__global__ void __launch_bounds__(256) gather_nodes(
    const float* __restrict__ x,
    const float* __restrict__ ea,
    const int* __restrict__ cnt,
    const int* __restrict__ cur,   // cur[n] == off[n] + cnt[n] after fill
    const int2* __restrict__ csr,
    float* __restrict__ A,
    float* __restrict__ B,
    int N_) {
    const int t = blockIdx.x * 256 + threadIdx.x;
    const int n = t >> 3;
    const int q = t & 7;
    if (n >= N_) return;
    const int c = cnt[n];
    const int2* __restrict__ lst = csr + (cur[n] - c);
    float ax = 0.f, ay = 0.f, az = 0.f, aw = 0.f;
    float bx = 0.f, by = 0.f, bz = 0.f, bw = 0.f;
    int2 p0 = make_int2(0, 0);
    if (c > 0) p0 = lst[0];
    for (int i = 0; i < c; ++i) {
        int2 p1 = p0;
        if (i + 1 < c) p1 = lst[i + 1];  // prefetch next entry
        const float4 xv = *(const float4*)(x + (size_t)p0.y * D + q * 4);
        const float4 ev = *(const float4*)(ea + (size_t)p0.x * D + q * 4);
        ax += xv.x; ay += xv.y; az += xv.z; aw += xv.w;
        bx += ev.x; by += ev.y; bz += ev.z; bw += ev.w;
        p0 = p1;
    }
    float4 An = { ax, ay, az, aw };
    float4 Bn = { bx, by, bz, bw };
    *(float4*)(A + (size_t)n * D + q * 4) = An;
    *(float4*)(B + (size_t)n * D + q * 4) = Bn;
}

// K5: per-node epilogue. Thread = node; weight loads are wave-uniform.
__global__ void __launch_bounds__(256) node_kernel(
    const float* __restrict__ x,
    const float* __restrict__ A,
    const float* __restrict__ B,
    const int* __restrict__ cnt,
    const float* __restrict__ W_rxnode,
    const float* __restrict__ P,
    float* __restrict__ out0,
    float* __restrict__ out1,
    int N_) {
    const int n = blockIdx.x * 256 + threadIdx.x;
    if (n >= N_) return;

    float xr[D];
    #pragma unroll
    for (int kq = 0; kq < D / 4; ++kq)
        *(float4*)(xr + kq * 4) = *(const float4*)(x + (size_t)n * D + kq * 4);

    {
        float o[D];
        #pragma unroll
        for (int j = 0; j < D; ++j) {
            float s = 0.f;
            #pragma unroll
            for (int k = 0; k < D; ++k) s += xr[k] * W_rxnode[j * D + k];
            o[j] = s;
        }
        #pragma unroll
        for (int kq = 0; kq < D / 4; ++kq)
            *(float4*)(out0 + (size_t)n * D + kq * 4) = *(const float4*)(o + kq * 4);
    }

    float Ar[D], Br[D];
    #pragma unroll
    for (int kq = 0; kq < D / 4; ++kq) {
        *(float4*)(Ar + kq * 4) = *(const float4*)(A + (size_t)n * D + kq * 4);
        *(float4*)(Br + kq * 4) = *(const float4*)(B + (size_t)n * D + kq * 4);
    }
    const float dg = (float)cnt[n];
    #pragma unroll
    for (int k = 0; k < D; ++k) xr[k] *= dg;  // fold deg into x row

    const float* __restrict__ Ps = P;
    const float* __restrict__ Pe = P + D * D;
    const float* __restrict__ Pr = P + 2 * D * D;
    {
        float o[D];
        #pragma unroll
        for (int j = 0; j < D; ++j) {
            float s = 0.f;
            #pragma unroll
            for (int k = 0; k < D; ++k) {
                s += Ar[k] * Ps[j * D + k];
                s += Br[k] * Pe[j * D + k];
                s += xr[k] * Pr[j * D + k];
            }
            o[j] = s;
        }
        #pragma unroll
        for (int kq = 0; kq < D / 4; ++kq)
            *(float4*)(out1 + (size_t)n * D + kq * 4) = *(const float4*)(o + kq * 4);
    }
}

extern "C" void kernel_launch(void* const* d_in, const int* in_sizes, int n_in,
                              void* d_out, int out_size, void* d_ws, size_t ws_size,
                              hipStream_t stream) {
    const float* x        = (const float*)d_in[0];
    const int*   ei       = (const int*)d_in[1];    // [2, E] (int32 view)
    const float* ea       = (const float*)d_in[2];  // [E, D]
    const float* W_src    = (const float*)d_in[3];
    const float* W_edge   = (const float*)d_in[4];
    const float* W_rx     = (const float*)d_in[5];
    const float* W_eu     = (const float*)d_in[6];
    const float* W_rxnode = (const float*)d_in[7];
    const float* W_aggr   = (const float*)d_in[8];

    const int N_ = in_sizes[0] / D;  // 100000
    const int E_ = in_sizes[2] / D;  // 2000000

    // ws layout (16B-aligned chunks first):
    // A[N*D] | B[N*D] | csr[E] int2 | cnt[N] | total[1] | cur[N] | P[3*D*D]
    float* A     = (float*)d_ws;
    float* B     = A + (size_t)N_ * D;
    int2*  csr   = (int2*)(B + (size_t)N_ * D);
    int*   cnt   = (int*)(csr + (size_t)E_);
    int*   total = cnt + N_;
    int*   cur   = total + 1;
    float* P     = (float*)(cur + N_);

    float* out0 = (float*)d_out;
    float* out1 = out0 + (size_t)N_ * D;

    // zero cnt + total only (A/B/csr fully overwritten each call)
    hipMemsetAsync(cnt, 0, (size_t)(N_ + 1) * sizeof(int), stream);

    combine_weights<<<1, dim3(32, 32), 0, stream>>>(W_src, W_edge, W_rx, W_eu, W_aggr, P);

    count_edges<<<(E_ + 255) / 256, 256, 0, stream>>>(ei, cnt, E_);
    alloc_nodes<<<(N_ + 255) / 256, 256, 0, stream>>>(cnt, cur, total, N_);
    fill_csr<<<(E_ + 255) / 256, 256, 0, stream>>>(ei, cur, csr, E_);

    gather_nodes<<<((N_ * 8) + 255) / 256, 256, 0, stream>>>(x, ea, cnt, cur, csr, A, B, N_);

    node_kernel<<<(N_ + 255) / 256, 256, 0, stream>>>(x, A, B, cnt, W_rxnode, P, out0, out1, N_);
}